// Round 2
// baseline (200.466 us; speedup 1.0000x reference)
//
#include <hip/hip_runtime.h>
#include <hip/hip_bf16.h>
#include <stdint.h>

// RBF dense layer: out[b][u] = exp(-gamma * max(|x_b|^2 + |k_u|^2 - 2*x_b.k_u, 0)) + bias[u]
// B=8192, D=512, U=4096, fp32 in/out. gamma = 1.0.
// Strategy: bf16 MFMA GEMM (m97/gemm_bt structure: 128x128 tile, BK=64,
// global_load_lds width=16, B^T layout so both operands are K-contiguous),
// with norms precomputed in fp32 and the exp epilogue fused into the GEMM.
// Fallback (ws too small): direct fp32 LDS-tiled sum((x-k)^2) kernel.

using short8 = __attribute__((ext_vector_type(8))) short;
using bf16x8 = __attribute__((ext_vector_type(8))) __bf16;
using f32x4  = __attribute__((ext_vector_type(4))) float;

#define GAMMA_F 1.0f

__device__ __forceinline__ unsigned short f2bf(float f) {
  unsigned u = __float_as_uint(f);
  u = (u + 0x7fffu + ((u >> 16) & 1u)) >> 16;  // RNE
  return (unsigned short)u;
}

// ---- pass 1: x (8192x512 f32) -> xb bf16 [8192][512], xsq[r] = sum_d x^2 ----
__global__ __launch_bounds__(256) void prep_x_kernel(const float* __restrict__ x,
                                                     unsigned short* __restrict__ xb,
                                                     float* __restrict__ xsq) {
  const int w = threadIdx.x >> 6, l = threadIdx.x & 63;
  const int r = blockIdx.x * 4 + w;
  const float4* xr = (const float4*)(x + (size_t)r * 512);
  float4 v0 = xr[l * 2 + 0];
  float4 v1 = xr[l * 2 + 1];
  float s = v0.x * v0.x + v0.y * v0.y + v0.z * v0.z + v0.w * v0.w
          + v1.x * v1.x + v1.y * v1.y + v1.z * v1.z + v1.w * v1.w;
  short8 p;
  p[0] = (short)f2bf(v0.x); p[1] = (short)f2bf(v0.y);
  p[2] = (short)f2bf(v0.z); p[3] = (short)f2bf(v0.w);
  p[4] = (short)f2bf(v1.x); p[5] = (short)f2bf(v1.y);
  p[6] = (short)f2bf(v1.z); p[7] = (short)f2bf(v1.w);
  *(short8*)(xb + (size_t)r * 512 + l * 8) = p;
#pragma unroll
  for (int o = 32; o > 0; o >>= 1) s += __shfl_xor(s, o);
  if (l == 0) xsq[r] = s;
}

// ---- pass 2: kernel (512x4096 f32 [d][u]) -> kbT bf16 [4096][512] + ksq[u] ----
__global__ __launch_bounds__(256) void prep_kT_kernel(const float* __restrict__ kern,
                                                      unsigned short* __restrict__ kbT,
                                                      float* __restrict__ ksq) {
  __shared__ unsigned short tile[64][65];
  const int t = threadIdx.x;
  const int u0 = blockIdx.x * 64, d0 = blockIdx.y * 64;
  const int c = t & 63, tq = t >> 6;
  float part = 0.f;
#pragma unroll
  for (int i = 0; i < 16; ++i) {
    const int r = tq * 16 + i;
    const float v = kern[(size_t)(d0 + r) * 4096 + u0 + c];
    part += v * v;
    tile[r][c] = f2bf(v);
  }
  atomicAdd(&ksq[u0 + c], part);  // ksq zeroed by memsetAsync; 8 adds/col total
  __syncthreads();
  const int dl = (t & 7) * 8;
#pragma unroll
  for (int h = 0; h < 2; ++h) {
    const int ul = (t >> 3) + h * 32;
    short8 v;
#pragma unroll
    for (int j = 0; j < 8; ++j) ((unsigned short*)&v)[j] = tile[dl + j][ul];
    *(short8*)(kbT + (size_t)(u0 + ul) * 512 + d0 + dl) = v;  // 16B/lane coalesced
  }
}

// ---- pass 3: GEMM + fused RBF epilogue (m97 structure) ----
__global__ __launch_bounds__(256) void rbf_gemm_kernel(
    const unsigned short* __restrict__ xb, const unsigned short* __restrict__ kbT,
    const float* __restrict__ xsq, const float* __restrict__ ksq,
    const float* __restrict__ bias, float* __restrict__ out) {
  __shared__ unsigned short As[128 * 64];  // [row][k] 16 KiB
  __shared__ unsigned short Bs[128 * 64];  // [col(u)][k] 16 KiB
  const int tid = threadIdx.x;
  const int w = tid >> 6, l = tid & 63;
  const int brow = blockIdx.y * 128, bcol = blockIdx.x * 128;
  const int wr = w >> 1, wc = w & 1;

  f32x4 acc[4][4] = {};

  const int srow = tid >> 3;
  const int scol = (tid & 7) * 8;
  const unsigned short* ga = xb + (size_t)(brow + srow) * 512 + scol;
  const unsigned short* gb = kbT + (size_t)(bcol + srow) * 512 + scol;
  unsigned short* lA = &As[w * 512];  // wave-uniform LDS base
  unsigned short* lB = &Bs[w * 512];

  for (int kk = 0; kk < 8; ++kk) {
    const int go = kk * 64;
#pragma unroll
    for (int i = 0; i < 4; ++i)
      __builtin_amdgcn_global_load_lds(
          (const __attribute__((address_space(1))) void*)(ga + (size_t)i * 32 * 512 + go),
          (__attribute__((address_space(3))) void*)(lA + i * 2048), 16, 0, 0);
#pragma unroll
    for (int i = 0; i < 4; ++i)
      __builtin_amdgcn_global_load_lds(
          (const __attribute__((address_space(1))) void*)(gb + (size_t)i * 32 * 512 + go),
          (__attribute__((address_space(3))) void*)(lB + i * 2048), 16, 0, 0);
    __syncthreads();
#pragma unroll
    for (int ki = 0; ki < 2; ++ki) {
      const int ko = ki * 32 + (l >> 4) * 8;
      bf16x8 a[4], b[4];
#pragma unroll
      for (int m = 0; m < 4; ++m)
        a[m] = *(const bf16x8*)&As[(wr * 64 + m * 16 + (l & 15)) * 64 + ko];
#pragma unroll
      for (int n = 0; n < 4; ++n)
        b[n] = *(const bf16x8*)&Bs[(wc * 64 + n * 16 + (l & 15)) * 64 + ko];
#pragma unroll
      for (int m = 0; m < 4; ++m)
#pragma unroll
        for (int n = 0; n < 4; ++n)
          acc[m][n] = __builtin_amdgcn_mfma_f32_16x16x32_bf16(a[m], b[n], acc[m][n], 0, 0, 0);
    }
    __syncthreads();
  }

  // epilogue: C/D layout col=lane&15, row=(lane>>4)*4+reg (m89/m91 verified)
  const int cl = l & 15, rg = (l >> 4) * 4;
#pragma unroll
  for (int n = 0; n < 4; ++n) {
    const int gc = bcol + wc * 64 + n * 16 + cl;
    const float kq = ksq[gc];
    const float bz = bias[gc];
#pragma unroll
    for (int m = 0; m < 4; ++m) {
      const int gr = brow + wr * 64 + m * 16 + rg;
      const float4 xq = *(const float4*)&xsq[gr];
      const float xq4[4] = {xq.x, xq.y, xq.z, xq.w};
#pragma unroll
      for (int j = 0; j < 4; ++j) {
        float d2 = xq4[j] + kq - 2.0f * acc[m][n][j];
        d2 = fmaxf(d2, 0.0f);
        out[(size_t)(gr + j) * 4096 + gc] = __expf(-GAMMA_F * d2) + bz;
      }
    }
  }
}

// ---- fallback (ws too small): direct fp32, d2 = sum_d (x-k)^2, LDS-tiled ----
__global__ __launch_bounds__(256) void rbf_direct_kernel(
    const float* __restrict__ x, const float* __restrict__ kern,
    const float* __restrict__ bias, float* __restrict__ out) {
  __shared__ float Xs[64][17];
  __shared__ float Ks[16][65];
  const int tid = threadIdx.x;
  const int brow = blockIdx.y * 64, bcol = blockIdx.x * 64;
  const int tr = (tid >> 4) * 4, tc = (tid & 15) * 4;
  float acc[4][4] = {};
  for (int k0 = 0; k0 < 512; k0 += 16) {
    {
      const int r = tid >> 2, c = (tid & 3) * 4;
      float4 v = *(const float4*)&x[(size_t)(brow + r) * 512 + k0 + c];
      Xs[r][c] = v.x; Xs[r][c + 1] = v.y; Xs[r][c + 2] = v.z; Xs[r][c + 3] = v.w;
    }
    {
      const int r = tid >> 4, c = (tid & 15) * 4;
      float4 v = *(const float4*)&kern[(size_t)(k0 + r) * 4096 + bcol + c];
      Ks[r][c] = v.x; Ks[r][c + 1] = v.y; Ks[r][c + 2] = v.z; Ks[r][c + 3] = v.w;
    }
    __syncthreads();
#pragma unroll
    for (int kk = 0; kk < 16; ++kk) {
      float a[4], b[4];
#pragma unroll
      for (int i = 0; i < 4; ++i) a[i] = Xs[tr + i][kk];
#pragma unroll
      for (int j = 0; j < 4; ++j) b[j] = Ks[kk][tc + j];
#pragma unroll
      for (int i = 0; i < 4; ++i)
#pragma unroll
        for (int j = 0; j < 4; ++j) {
          float d = a[i] - b[j];
          acc[i][j] = fmaf(d, d, acc[i][j]);
        }
    }
    __syncthreads();
  }
#pragma unroll
  for (int i = 0; i < 4; ++i)
#pragma unroll
    for (int j = 0; j < 4; ++j)
      out[(size_t)(brow + tr + i) * 4096 + bcol + tc + j] =
          __expf(-GAMMA_F * acc[i][j]) + bias[bcol + tc + j];
}

extern "C" void kernel_launch(void* const* d_in, const int* in_sizes, int n_in,
                              void* d_out, int out_size, void* d_ws, size_t ws_size,
                              hipStream_t stream) {
  const float* x    = (const float*)d_in[0];   // 8192*512
  const float* kern = (const float*)d_in[1];   // 512*4096
  const float* bias = (const float*)d_in[2];   // 4096
  float* out = (float*)d_out;                  // 8192*4096 f32

  const size_t NEED = 8388608 /*xb*/ + 4194304 /*kbT*/ + 32768 /*xsq*/ + 16384 /*ksq*/;
  if (ws_size < NEED) {
    // correctness fallback, no workspace
    rbf_direct_kernel<<<dim3(64, 128), 256, 0, stream>>>(x, kern, bias, out);
    return;
  }

  char* ws = (char*)d_ws;
  unsigned short* xb  = (unsigned short*)(ws);                 // 8 MiB bf16 x
  unsigned short* kbT = (unsigned short*)(ws + 8388608);       // 4 MiB bf16 kernel^T
  float* xsq = (float*)(ws + 8388608 + 4194304);               // 32 KiB row norms
  float* ksq = xsq + 8192;                                     // 16 KiB col norms

  hipMemsetAsync(ksq, 0, 4096 * sizeof(float), stream);
  prep_x_kernel<<<2048, 256, 0, stream>>>(x, xb, xsq);
  prep_kT_kernel<<<dim3(64, 8), 256, 0, stream>>>(kern, kbT, ksq);
  rbf_gemm_kernel<<<dim3(32, 64), 256, 0, stream>>>(xb, kbT, xsq, ksq, bias, out);
}